// Round 4
// baseline (607.196 us; speedup 1.0000x reference)
//
#include <hip/hip_runtime.h>

typedef _Float16 half8 __attribute__((ext_vector_type(8)));
typedef _Float16 half4 __attribute__((ext_vector_type(4)));
typedef float    f32x4 __attribute__((ext_vector_type(4)));

#define MFMA32(a,b,c) __builtin_amdgcn_mfma_f32_16x16x32_f16(a,b,c,0,0,0)

#if __has_builtin(__builtin_amdgcn_exp2f)
#define EXP2F(x) __builtin_amdgcn_exp2f(x)
#else
#define EXP2F(x) exp2f(x)
#endif

// scale = DH^-0.5 = 1/8, folded together with log2(e) into Q so softmax uses exp2.
static constexpr float SCALE_LOG2E = 0.18033688011112042f;

static constexpr size_t QH_OFF = 0;
static constexpr size_t KH_OFF = (size_t)8  << 20;
static constexpr size_t VT_OFF = (size_t)16 << 20;
static constexpr size_t LS_OFF = (size_t)24 << 20;
static constexpr size_t O_OFF  = (size_t)25 << 20;
static constexpr size_t LPART  = (size_t)4*8*2048;       // floats per L partial
static constexpr size_t OPART  = (size_t)8192*512;       // halves per O partial

// ---------------------------------------------------------------------------
// K1: qkv projection. C[8192,1536] = X[8192,512] @ W[512,1536] + b.
// Scatters to Qh[b][h][n][64] (xSCALE_LOG2E), Kh[b][h][n][64], Vt[b][h][64][n], all f16.
// ---------------------------------------------------------------------------
__global__ __launch_bounds__(256)
void k_qkv(const float* __restrict__ x, const float* __restrict__ w,
           const float* __restrict__ bias, _Float16* __restrict__ Qh,
           _Float16* __restrict__ Kh, _Float16* __restrict__ Vt)
{
  __shared__ __align__(16) _Float16 Xs[64*40];
  __shared__ __align__(16) _Float16 Wt[64*40];
  const int tid = threadIdx.x;
  const int wv = tid >> 6, lane = tid & 63, l15 = lane & 15, qd = lane >> 4;
  const int row0 = blockIdx.x * 64, col0 = blockIdx.y * 64;

  const int xr = tid >> 2, xc = (tid & 3) * 8;
  const int wk = tid >> 3, wc = (tid & 7) * 8;

  f32x4 acc[4] = {{0.f,0.f,0.f,0.f},{0.f,0.f,0.f,0.f},{0.f,0.f,0.f,0.f},{0.f,0.f,0.f,0.f}};

  for (int k0 = 0; k0 < 512; k0 += 32) {
    f32x4 a0 = *(const f32x4*)(x + (size_t)(row0 + xr) * 512 + k0 + xc);
    f32x4 a1 = *(const f32x4*)(x + (size_t)(row0 + xr) * 512 + k0 + xc + 4);
    f32x4 b0 = *(const f32x4*)(w + (size_t)(k0 + wk) * 1536 + col0 + wc);
    f32x4 b1 = *(const f32x4*)(w + (size_t)(k0 + wk) * 1536 + col0 + wc + 4);
    half8 hx;
#pragma unroll
    for (int j = 0; j < 4; j++) { hx[j] = (_Float16)a0[j]; hx[j+4] = (_Float16)a1[j]; }
    *(half8*)&Xs[xr*40 + xc] = hx;
#pragma unroll
    for (int j = 0; j < 4; j++) {
      Wt[(wc+j  )*40 + wk] = (_Float16)b0[j];
      Wt[(wc+j+4)*40 + wk] = (_Float16)b1[j];
    }
    __syncthreads();
    half8 af = *(const half8*)&Xs[(wv*16 + l15)*40 + qd*8];
#pragma unroll
    for (int ct = 0; ct < 4; ct++) {
      half8 bf = *(const half8*)&Wt[(ct*16 + l15)*40 + qd*8];
      acc[ct] = MFMA32(af, bf, acc[ct]);
    }
    __syncthreads();
  }
#pragma unroll
  for (int ct = 0; ct < 4; ct++) {
    const int c = col0 + ct*16 + l15;
    const int sec = c >> 9, hh = (c >> 6) & 7, d = c & 63;
    const float bv = bias[c];
#pragma unroll
    for (int i = 0; i < 4; i++) {
      const int row = row0 + wv*16 + qd*4 + i;
      const int bb = row >> 11, n = row & 2047;
      float v = acc[ct][i] + bv;
      if (sec == 0)
        Qh[((size_t)((bb*8 + hh)*2048 + n))*64 + d] = (_Float16)(v * SCALE_LOG2E);
      else if (sec == 1)
        Kh[((size_t)((bb*8 + hh)*2048 + n))*64 + d] = (_Float16)v;
      else
        Vt[((size_t)((bb*8 + hh)*64 + d))*2048 + n] = (_Float16)v;
    }
  }
}

// ---------------------------------------------------------------------------
// K2: pass 1 — partial softmax denominators over an m-quarter. K B-fragments
// read DIRECT from global (L2-resident; no LDS staging, no in-loop barriers).
// Plain stores to per-mq partial buffers. Grid 1024: blockIdx = nt*16+(b*4+mq).
// ---------------------------------------------------------------------------
__global__ __launch_bounds__(256, 3)
void k_pass1(const _Float16* __restrict__ Qh, const _Float16* __restrict__ Kh,
             const float* __restrict__ th1, float* __restrict__ Lsum)
{
  __shared__ float Lred[2][8][16];                // 1 KB
  const int tid = threadIdx.x;
  const int wv = tid >> 6, lane = tid & 63, l15 = lane & 15, qd = lane >> 4;
  const int s = blockIdx.x & 15, nt = blockIdx.x >> 4;
  const int b = s >> 2, mq = s & 3;
  const int ns = wv >> 1, mp = wv & 1;
  const int n0 = nt*32 + ns*16;

  half8 qf[8][2];
#pragma unroll
  for (int h = 0; h < 8; h++)
#pragma unroll
    for (int kc = 0; kc < 2; kc++)
      qf[h][kc] = *(const half8*)(Qh + ((size_t)((b*8 + h)*2048 + n0 + l15))*64 + kc*32 + qd*8);

  f32x4 lsum[8];
#pragma unroll
  for (int g = 0; g < 8; g++) lsum[g] = (f32x4){0.f,0.f,0.f,0.f};

  for (int it = 0; it < 16; it++) {
    const int mm = mq*512 + it*32 + mp*16;   // this wave's 16m chunk
    f32x4 sp[8];
#pragma unroll
    for (int g = 0; g < 8; g++) sp[g] = (f32x4){0.f,0.f,0.f,0.f};
#pragma unroll
    for (int h = 0; h < 8; h++) {
      const _Float16* kb = Kh + ((size_t)((b*8 + h)*2048 + mm + l15))*64 + qd*8;
      half8 kb0 = *(const half8*)kb;
      half8 kb1 = *(const half8*)(kb + 32);
      f32x4 s4 = {0.f,0.f,0.f,0.f};
      s4 = MFMA32(qf[h][0], kb0, s4);
      s4 = MFMA32(qf[h][1], kb1, s4);
      const float* t1h = th1 + h;    // th1[g*8+h], g varies
#pragma unroll
      for (int g = 0; g < 8; g++)
        sp[g] += t1h[g*8] * s4;
    }
#pragma unroll
    for (int g = 0; g < 8; g++)
#pragma unroll
      for (int i = 0; i < 4; i++)
        lsum[g][i] += EXP2F(sp[g][i]);
  }

  // reduce over the 16 m-columns held across l15 lanes
#pragma unroll
  for (int g = 0; g < 8; g++)
#pragma unroll
    for (int i = 0; i < 4; i++) {
      float v = lsum[g][i];
      v += __shfl_xor(v, 1);
      v += __shfl_xor(v, 2);
      v += __shfl_xor(v, 4);
      v += __shfl_xor(v, 8);
      lsum[g][i] = v;
    }
  if (mp == 1 && l15 == 0) {
#pragma unroll
    for (int g = 0; g < 8; g++)
#pragma unroll
      for (int i = 0; i < 4; i++)
        Lred[ns][g][qd*4 + i] = lsum[g][i];
  }
  __syncthreads();
  if (mp == 0 && l15 == 0) {
    float* Lp = Lsum + (size_t)mq * LPART;
#pragma unroll
    for (int g = 0; g < 8; g++)
#pragma unroll
      for (int i = 0; i < 4; i++)
        Lp[(size_t)(b*8 + g)*2048 + n0 + qd*4 + i] = lsum[g][i] + Lred[ns][g][qd*4 + i];
  }
}

// ---------------------------------------------------------------------------
// K3: pass 2 over an m-quarter. K and V fragments direct from global (L2);
// LDS only for the W C-layout -> A-layout transform (17 KB). No spilling:
// launch_bounds(256,2) caps VGPR at 256 > working set (~230).
// Grid 1024: blockIdx = nt*16 + (b*4+mq) (XCD swizzle).
// ---------------------------------------------------------------------------
__global__ __launch_bounds__(256, 2)
void k_pass2(const _Float16* __restrict__ Qh, const _Float16* __restrict__ Kh,
             const _Float16* __restrict__ Vt, const float* __restrict__ Lsum,
             const float* __restrict__ th1, const float* __restrict__ th2,
             _Float16* __restrict__ Obuf)
{
  __shared__ __align__(16) _Float16 Wl[256*34];   // 17408 B : [(ns*8+g)*16+n][32m +2]
  const int tid = threadIdx.x;
  const int wv = tid >> 6, lane = tid & 63, l15 = lane & 15, qd = lane >> 4;
  const int s = blockIdx.x & 15, nt = blockIdx.x >> 4;
  const int b = s >> 2, mq = s & 3;
  const int ns = wv >> 1, mp = wv & 1, p = mp;
  const int n0 = nt*32 + ns*16;

  // seed = -log2(sum of 4 L partials): normalization folded into exp2
  f32x4 nlg[8];
#pragma unroll
  for (int h = 0; h < 8; h++)
#pragma unroll
    for (int i = 0; i < 4; i++) {
      const size_t off = (size_t)(b*8 + h)*2048 + n0 + qd*4 + i;
      float l = Lsum[off] + Lsum[off + LPART] + Lsum[off + 2*LPART] + Lsum[off + 3*LPART];
      nlg[h][i] = -__log2f(l);
    }

  half8 qf[8][2];
#pragma unroll
  for (int h = 0; h < 8; h++)
#pragma unroll
    for (int kc = 0; kc < 2; kc++)
      qf[h][kc] = *(const half8*)(Qh + ((size_t)((b*8 + h)*2048 + n0 + l15))*64 + kc*32 + qd*8);

  f32x4 og[4][4];
#pragma unroll
  for (int gg = 0; gg < 4; gg++)
#pragma unroll
    for (int dt = 0; dt < 4; dt++)
      og[gg][dt] = (f32x4){0.f,0.f,0.f,0.f};

  const _Float16* vbase = Vt + (size_t)b*512*2048;

  for (int it = 0; it < 16; it++) {
    const int mm = mq*512 + it*32;

    // scores for this wave's 16m chunk (K direct from global), th1-mixed, seeded
    f32x4 sp[8];
#pragma unroll
    for (int g = 0; g < 8; g++) sp[g] = nlg[g];
#pragma unroll
    for (int h = 0; h < 8; h++) {
      const _Float16* kb = Kh + ((size_t)((b*8 + h)*2048 + mm + mp*16 + l15))*64 + qd*8;
      half8 kb0 = *(const half8*)kb;
      half8 kb1 = *(const half8*)(kb + 32);
      f32x4 s4 = {0.f,0.f,0.f,0.f};
      s4 = MFMA32(qf[h][0], kb0, s4);
      s4 = MFMA32(qf[h][1], kb1, s4);
      const float* t1h = th1 + h;
#pragma unroll
      for (int g = 0; g < 8; g++)
        sp[g] += t1h[g*8] * s4;
    }
    // p = exp2(sp) is already normalized; th2 mix across heads
    f32x4 wacc[8];
#pragma unroll
    for (int g = 0; g < 8; g++) wacc[g] = (f32x4){0.f,0.f,0.f,0.f};
#pragma unroll
    for (int g = 0; g < 8; g++) {
      f32x4 pr;
#pragma unroll
      for (int i = 0; i < 4; i++)
        pr[i] = EXP2F(sp[g][i]);
      const float* t2g = th2 + g;
#pragma unroll
      for (int g2 = 0; g2 < 8; g2++)
        wacc[g2] += t2g[g2*8] * pr;
    }
    // write W (C-layout -> LDS rows) for this (ns, m-chunk)
#pragma unroll
    for (int g = 0; g < 8; g++)
#pragma unroll
      for (int i = 0; i < 4; i++)
        Wl[((ns*8 + g)*16 + qd*4 + i)*34 + mp*16 + l15] = (_Float16)wacc[g][i];
    __syncthreads();

    // PV: this wave handles g in [p*4, p*4+4) over the full 32m.
    // V B-fragments contiguous in Vt -> direct global (L2) loads.
#pragma unroll
    for (int gg = 0; gg < 4; gg++) {
      const int g = p*4 + gg;
      half8 af = *(const half8*)&Wl[((ns*8 + g)*16 + l15)*34 + qd*8];
#pragma unroll
      for (int dt = 0; dt < 4; dt++) {
        half8 bf = *(const half8*)(vbase + (size_t)(g*64 + dt*16 + l15)*2048 + mm + qd*8);
        og[gg][dt] = MFMA32(af, bf, og[gg][dt]);
      }
    }
    __syncthreads();
  }

  _Float16* Op = Obuf + (size_t)mq * OPART;   // partial buffer for this m-quarter
#pragma unroll
  for (int gg = 0; gg < 4; gg++)
#pragma unroll
    for (int dt = 0; dt < 4; dt++)
#pragma unroll
      for (int i = 0; i < 4; i++) {
        const int col = (p*4 + gg)*64 + dt*16 + l15;
        const int n = n0 + qd*4 + i;
        Op[((size_t)(b*2048 + n))*512 + col] = (_Float16)og[gg][dt][i];
      }
}

// ---------------------------------------------------------------------------
// K4: output projection summing 4 partial O buffers.
// out[8192,512] = (O0+O1+O2+O3) @ w_out[512,512] + b_out (fp32 out)
// ---------------------------------------------------------------------------
__global__ __launch_bounds__(256)
void k_oproj(const _Float16* __restrict__ Ob, const float* __restrict__ w,
             const float* __restrict__ bias, float* __restrict__ out)
{
  __shared__ __align__(16) _Float16 Xs[64*40];
  __shared__ __align__(16) _Float16 Wt[64*40];
  const int tid = threadIdx.x;
  const int wv = tid >> 6, lane = tid & 63, l15 = lane & 15, qd = lane >> 4;
  const int row0 = blockIdx.x * 64, col0 = blockIdx.y * 64;
  const int xr = tid >> 2, xc = (tid & 3) * 8;
  const int wk = tid >> 3, wc = (tid & 7) * 8;

  f32x4 acc[4] = {{0.f,0.f,0.f,0.f},{0.f,0.f,0.f,0.f},{0.f,0.f,0.f,0.f},{0.f,0.f,0.f,0.f}};

  for (int k0 = 0; k0 < 512; k0 += 32) {
    const size_t idx = (size_t)(row0 + xr)*512 + k0 + xc;
    half8 a0 = *(const half8*)(Ob + idx);
    half8 a1 = *(const half8*)(Ob + OPART + idx);
    half8 a2 = *(const half8*)(Ob + 2*OPART + idx);
    half8 a3 = *(const half8*)(Ob + 3*OPART + idx);
    *(half8*)&Xs[xr*40 + xc] = (a0 + a1) + (a2 + a3);
    f32x4 b0 = *(const f32x4*)(w + (size_t)(k0 + wk)*512 + col0 + wc);
    f32x4 b1 = *(const f32x4*)(w + (size_t)(k0 + wk)*512 + col0 + wc + 4);
#pragma unroll
    for (int j = 0; j < 4; j++) {
      Wt[(wc+j  )*40 + wk] = (_Float16)b0[j];
      Wt[(wc+j+4)*40 + wk] = (_Float16)b1[j];
    }
    __syncthreads();
    half8 af = *(const half8*)&Xs[(wv*16 + l15)*40 + qd*8];
#pragma unroll
    for (int ct = 0; ct < 4; ct++) {
      half8 bf = *(const half8*)&Wt[(ct*16 + l15)*40 + qd*8];
      acc[ct] = MFMA32(af, bf, acc[ct]);
    }
    __syncthreads();
  }
#pragma unroll
  for (int ct = 0; ct < 4; ct++) {
    const int c = col0 + ct*16 + l15;
    const float bv = bias[c];
#pragma unroll
    for (int i = 0; i < 4; i++) {
      const int row = row0 + wv*16 + qd*4 + i;
      out[(size_t)row*512 + c] = acc[ct][i] + bv;
    }
  }
}

// ---------------------------------------------------------------------------
extern "C" void kernel_launch(void* const* d_in, const int* in_sizes, int n_in,
                              void* d_out, int out_size, void* d_ws, size_t ws_size,
                              hipStream_t stream)
{
  (void)in_sizes; (void)n_in; (void)out_size;
  const float* x     = (const float*)d_in[0];
  const float* w_qkv = (const float*)d_in[1];
  const float* b_qkv = (const float*)d_in[2];
  const float* th1   = (const float*)d_in[3];
  const float* th2   = (const float*)d_in[4];
  const float* w_out = (const float*)d_in[5];
  const float* b_out = (const float*)d_in[6];
  float* out = (float*)d_out;

  char* ws = (char*)d_ws;
  _Float16* Qh   = (_Float16*)(ws + QH_OFF);
  _Float16* Kh   = (_Float16*)(ws + KH_OFF);
  _Float16* Vt   = (_Float16*)(ws + VT_OFF);
  float*    Lsum = (float*)   (ws + LS_OFF);
  _Float16* Obuf = (_Float16*)(ws + O_OFF);
  if (ws_size < ((size_t)58 << 20)) return;  // need 58 MB scratch

  k_qkv  <<<dim3(128, 24), 256, 0, stream>>>(x, w_qkv, b_qkv, Qh, Kh, Vt);
  k_pass1<<<dim3(1024),    256, 0, stream>>>(Qh, Kh, th1, Lsum);
  k_pass2<<<dim3(1024),    256, 0, stream>>>(Qh, Kh, Vt, Lsum, th1, th2, Obuf);
  k_oproj<<<dim3(128, 8),  256, 0, stream>>>(Obuf, w_out, b_out, out);
}

// Round 5
// 531.807 us; speedup vs baseline: 1.1418x; 1.1418x over previous
//
#include <hip/hip_runtime.h>

typedef _Float16 half8 __attribute__((ext_vector_type(8)));
typedef _Float16 half4 __attribute__((ext_vector_type(4)));
typedef float    f32x4 __attribute__((ext_vector_type(4)));

#define MFMA32(a,b,c) __builtin_amdgcn_mfma_f32_16x16x32_f16(a,b,c,0,0,0)

#if __has_builtin(__builtin_amdgcn_exp2f)
#define EXP2F(x) __builtin_amdgcn_exp2f(x)
#else
#define EXP2F(x) exp2f(x)
#endif

// XOR-swizzled LDS layout: 128 rows x 64 halves, 8-half blocks swizzled by row.
// addr (halves) = row*64 + ((col8 ^ (row&7))<<3). All frag reads/writes <=2-way.
#define LADDR(row, col8) ((((row)) << 6) + ((((col8) ^ ((row) & 7))) << 3))

// scale = DH^-0.5 = 1/8, folded together with log2(e) into Q so softmax uses exp2.
static constexpr float SCALE_LOG2E = 0.18033688011112042f;

static constexpr size_t QH_OFF = 0;
static constexpr size_t KH_OFF = (size_t)8  << 20;
static constexpr size_t VT_OFF = (size_t)16 << 20;
static constexpr size_t LS_OFF = (size_t)24 << 20;
static constexpr size_t O_OFF  = (size_t)25 << 20;
static constexpr size_t LPART  = (size_t)4*8*2048;       // floats per L partial
static constexpr size_t OPART  = (size_t)8192*512;       // halves per O partial

// ---------------------------------------------------------------------------
// K1: qkv projection. C[8192,1536] = X[8192,512] @ W[512,1536] + b.
// Scatters to Qh[b][h][n][64] (xSCALE_LOG2E), Kh[b][h][n][64], Vt[b][h][64][n], all f16.
// ---------------------------------------------------------------------------
__global__ __launch_bounds__(256)
void k_qkv(const float* __restrict__ x, const float* __restrict__ w,
           const float* __restrict__ bias, _Float16* __restrict__ Qh,
           _Float16* __restrict__ Kh, _Float16* __restrict__ Vt)
{
  __shared__ __align__(16) _Float16 Xs[64*40];
  __shared__ __align__(16) _Float16 Wt[64*40];
  const int tid = threadIdx.x;
  const int wv = tid >> 6, lane = tid & 63, l15 = lane & 15, qd = lane >> 4;
  const int row0 = blockIdx.x * 64, col0 = blockIdx.y * 64;

  const int xr = tid >> 2, xc = (tid & 3) * 8;
  const int wk = tid >> 3, wc = (tid & 7) * 8;

  f32x4 acc[4] = {{0.f,0.f,0.f,0.f},{0.f,0.f,0.f,0.f},{0.f,0.f,0.f,0.f},{0.f,0.f,0.f,0.f}};

  for (int k0 = 0; k0 < 512; k0 += 32) {
    f32x4 a0 = *(const f32x4*)(x + (size_t)(row0 + xr) * 512 + k0 + xc);
    f32x4 a1 = *(const f32x4*)(x + (size_t)(row0 + xr) * 512 + k0 + xc + 4);
    f32x4 b0 = *(const f32x4*)(w + (size_t)(k0 + wk) * 1536 + col0 + wc);
    f32x4 b1 = *(const f32x4*)(w + (size_t)(k0 + wk) * 1536 + col0 + wc + 4);
    half8 hx;
#pragma unroll
    for (int j = 0; j < 4; j++) { hx[j] = (_Float16)a0[j]; hx[j+4] = (_Float16)a1[j]; }
    *(half8*)&Xs[xr*40 + xc] = hx;
#pragma unroll
    for (int j = 0; j < 4; j++) {
      Wt[(wc+j  )*40 + wk] = (_Float16)b0[j];
      Wt[(wc+j+4)*40 + wk] = (_Float16)b1[j];
    }
    __syncthreads();
    half8 af = *(const half8*)&Xs[(wv*16 + l15)*40 + qd*8];
#pragma unroll
    for (int ct = 0; ct < 4; ct++) {
      half8 bf = *(const half8*)&Wt[(ct*16 + l15)*40 + qd*8];
      acc[ct] = MFMA32(af, bf, acc[ct]);
    }
    __syncthreads();
  }
#pragma unroll
  for (int ct = 0; ct < 4; ct++) {
    const int c = col0 + ct*16 + l15;
    const int sec = c >> 9, hh = (c >> 6) & 7, d = c & 63;
    const float bv = bias[c];
#pragma unroll
    for (int i = 0; i < 4; i++) {
      const int row = row0 + wv*16 + qd*4 + i;
      const int bb = row >> 11, n = row & 2047;
      float v = acc[ct][i] + bv;
      if (sec == 0)
        Qh[((size_t)((bb*8 + hh)*2048 + n))*64 + d] = (_Float16)(v * SCALE_LOG2E);
      else if (sec == 1)
        Kh[((size_t)((bb*8 + hh)*2048 + n))*64 + d] = (_Float16)v;
      else
        Vt[((size_t)((bb*8 + hh)*64 + d))*2048 + n] = (_Float16)v;
    }
  }
}

// ---------------------------------------------------------------------------
// K2: pass 1 — partial softmax denominators over an m-quarter, 3-phase style.
// Per 64m iter: (a) wave=m-chunk computes raw S_h (A=K so C packs b64) -> Sb;
// (b) wave=h-pair th1-mixes (16 SGPR consts), exp2, accumulates l per (h,n).
// Grid 2048 = 128nt x (4b x 4mq); 16n rows per block. No atomics.
// ---------------------------------------------------------------------------
__global__ __launch_bounds__(256, 3)
void k_pass1(const _Float16* __restrict__ Qh, const _Float16* __restrict__ Kh,
             const float* __restrict__ th1, float* __restrict__ Lsum)
{
  __shared__ __align__(16) _Float16 Qs[128*64];  // [h*16+n][64d], swizzled
  __shared__ __align__(16) _Float16 Sb[128*64];  // [h*16+n][64m], swizzled
  const int tid = threadIdx.x;
  const int wv = __builtin_amdgcn_readfirstlane(tid >> 6);
  const int lane = tid & 63, l15 = lane & 15, qd = lane >> 4;
  const int s = blockIdx.x & 15, nt = blockIdx.x >> 4;
  const int b = s >> 2, mq = s & 3;
  const int n0 = nt << 4;

  float t1c[2][8];
#pragma unroll
  for (int u = 0; u < 2; u++)
#pragma unroll
    for (int h = 0; h < 8; h++)
      t1c[u][h] = th1[(wv*2+u)*8 + h];

  // stage Q block: 8h x 16n x 64d
#pragma unroll
  for (int jj = 0; jj < 4; jj++) {
    const int c = tid + 256*jj;
    const int row = c >> 3, dc = c & 7;
    const int h = row >> 4, n = row & 15;
    *(half8*)&Qs[LADDR(row, dc)] =
      *(const half8*)(Qh + ((size_t)((b*8+h)*2048 + n0 + n))*64 + dc*8);
  }
  __syncthreads();

  float lacc0 = 0.f, lacc1 = 0.f;

  for (int it = 0; it < 8; it++) {
    // (a) raw scores for this wave's 16m chunk, all 8 h. A=K(l15=m), B=Q(l15=n)
    // -> C: row=qd*4+i=m, col=l15=n  => 4 consecutive m per lane => b64 pack.
    const int mmw = mq*512 + it*64 + wv*16;
#pragma unroll
    for (int h = 0; h < 8; h++) {
      half8 qa0 = *(const half8*)&Qs[LADDR(h*16 + l15, qd)];
      half8 qa1 = *(const half8*)&Qs[LADDR(h*16 + l15, 4 + qd)];
      const _Float16* kp = Kh + ((size_t)((b*8+h)*2048 + mmw + l15))*64 + qd*8;
      half8 kb0 = *(const half8*)kp;
      half8 kb1 = *(const half8*)(kp + 32);
      f32x4 s4 = {0.f,0.f,0.f,0.f};
      s4 = MFMA32(kb0, qa0, s4);
      s4 = MFMA32(kb1, qa1, s4);
      half4 sh;
#pragma unroll
      for (int i = 0; i < 4; i++) sh[i] = (_Float16)s4[i];
      const int row = h*16 + l15;           // n-row
      const int col = wv*16 + qd*4;         // m-col (4 packed)
      *(half4*)&Sb[LADDR(row, col >> 3) + (col & 7)] = sh;
    }
    __syncthreads();

    // (b) th1-mix for this wave's h-pair over all 64m (A-frag reads: l15=n)
    float sa[2][2][8];
#pragma unroll
    for (int u = 0; u < 2; u++)
#pragma unroll
      for (int mc = 0; mc < 2; mc++)
#pragma unroll
        for (int j = 0; j < 8; j++) sa[u][mc][j] = 0.f;
#pragma unroll
    for (int hp = 0; hp < 8; hp++) {
      half8 s0 = *(const half8*)&Sb[LADDR(hp*16 + l15, qd)];
      half8 s1 = *(const half8*)&Sb[LADDR(hp*16 + l15, 4 + qd)];
#pragma unroll
      for (int j = 0; j < 8; j++) {
        sa[0][0][j] = fmaf((float)s0[j], t1c[0][hp], sa[0][0][j]);
        sa[0][1][j] = fmaf((float)s1[j], t1c[0][hp], sa[0][1][j]);
        sa[1][0][j] = fmaf((float)s0[j], t1c[1][hp], sa[1][0][j]);
        sa[1][1][j] = fmaf((float)s1[j], t1c[1][hp], sa[1][1][j]);
      }
    }
#pragma unroll
    for (int mc = 0; mc < 2; mc++)
#pragma unroll
      for (int j = 0; j < 8; j++) {
        lacc0 += EXP2F(sa[0][mc][j]);
        lacc1 += EXP2F(sa[1][mc][j]);
      }
    __syncthreads();
  }

  // reduce the per-lane m-partials across qd (lane bits 4,5)
  lacc0 += __shfl_xor(lacc0, 16); lacc0 += __shfl_xor(lacc0, 32);
  lacc1 += __shfl_xor(lacc1, 16); lacc1 += __shfl_xor(lacc1, 32);
  if (qd == 0) {
    float* Lp = Lsum + (size_t)mq * LPART + (size_t)(b*8 + wv*2)*2048 + n0 + l15;
    Lp[0]    = lacc0;
    Lp[2048] = lacc1;
  }
}

// ---------------------------------------------------------------------------
// K3: pass 2 over an m-quarter, 3-phase. (a) raw S -> Sb; (b) th1-mix + exp2
// (seeded with -log2 l) -> P f16 -> Pb; (c) th2-mix reads P A-frags and builds
// the PV A-fragment IN REGISTERS (layouts coincide pointwise), then PV MFMA
// with V direct from global. 2 barriers/iter. Partial O per mq.
// ---------------------------------------------------------------------------
__global__ __launch_bounds__(256, 3)
void k_pass2(const _Float16* __restrict__ Qh, const _Float16* __restrict__ Kh,
             const _Float16* __restrict__ Vt, const float* __restrict__ Lsum,
             const float* __restrict__ th1, const float* __restrict__ th2,
             _Float16* __restrict__ Obuf)
{
  __shared__ __align__(16) _Float16 Qs[128*64];
  __shared__ __align__(16) _Float16 Sb[128*64];
  __shared__ __align__(16) _Float16 Pb[128*64];
  const int tid = threadIdx.x;
  const int wv = __builtin_amdgcn_readfirstlane(tid >> 6);
  const int lane = tid & 63, l15 = lane & 15, qd = lane >> 4;
  const int s = blockIdx.x & 15, nt = blockIdx.x >> 4;
  const int b = s >> 2, mq = s & 3;
  const int n0 = nt << 4;

  float t1c[2][8], t2c[2][8];
#pragma unroll
  for (int u = 0; u < 2; u++)
#pragma unroll
    for (int h = 0; h < 8; h++) {
      t1c[u][h] = th1[(wv*2+u)*8 + h];
      t2c[u][h] = th2[(wv*2+u)*8 + h];
    }

  // per-lane -log2(l) for this wave's h-pair at row n = l15
  float nlg[2];
#pragma unroll
  for (int u = 0; u < 2; u++) {
    const size_t off = (size_t)(b*8 + wv*2 + u)*2048 + n0 + l15;
    float l = Lsum[off] + Lsum[off + LPART] + Lsum[off + 2*LPART] + Lsum[off + 3*LPART];
    nlg[u] = -__log2f(l);
  }

#pragma unroll
  for (int jj = 0; jj < 4; jj++) {
    const int c = tid + 256*jj;
    const int row = c >> 3, dc = c & 7;
    const int h = row >> 4, n = row & 15;
    *(half8*)&Qs[LADDR(row, dc)] =
      *(const half8*)(Qh + ((size_t)((b*8+h)*2048 + n0 + n))*64 + dc*8);
  }
  __syncthreads();

  f32x4 og[2][4];
#pragma unroll
  for (int u = 0; u < 2; u++)
#pragma unroll
    for (int dt = 0; dt < 4; dt++)
      og[u][dt] = (f32x4){0.f,0.f,0.f,0.f};

  const _Float16* vbase = Vt + (size_t)(b*8)*64*2048;

  // phase (a) for iter 0
  {
    const int mmw = mq*512 + wv*16;
#pragma unroll
    for (int h = 0; h < 8; h++) {
      half8 qa0 = *(const half8*)&Qs[LADDR(h*16 + l15, qd)];
      half8 qa1 = *(const half8*)&Qs[LADDR(h*16 + l15, 4 + qd)];
      const _Float16* kp = Kh + ((size_t)((b*8+h)*2048 + mmw + l15))*64 + qd*8;
      half8 kb0 = *(const half8*)kp;
      half8 kb1 = *(const half8*)(kp + 32);
      f32x4 s4 = {0.f,0.f,0.f,0.f};
      s4 = MFMA32(kb0, qa0, s4);
      s4 = MFMA32(kb1, qa1, s4);
      half4 sh;
#pragma unroll
      for (int i = 0; i < 4; i++) sh[i] = (_Float16)s4[i];
      const int row = h*16 + l15;
      const int col = wv*16 + qd*4;
      *(half4*)&Sb[LADDR(row, col >> 3) + (col & 7)] = sh;
    }
  }
  __syncthreads();

  for (int it = 0; it < 8; it++) {
    const int mm = mq*512 + it*64;

    // (b) th1-mix + exp2 -> P (f16) for this wave's h-pair, all 64m
    float sa[2][2][8];
#pragma unroll
    for (int u = 0; u < 2; u++)
#pragma unroll
      for (int mc = 0; mc < 2; mc++)
#pragma unroll
        for (int j = 0; j < 8; j++) sa[u][mc][j] = nlg[u];
#pragma unroll
    for (int hp = 0; hp < 8; hp++) {
      half8 s0 = *(const half8*)&Sb[LADDR(hp*16 + l15, qd)];
      half8 s1 = *(const half8*)&Sb[LADDR(hp*16 + l15, 4 + qd)];
#pragma unroll
      for (int j = 0; j < 8; j++) {
        sa[0][0][j] = fmaf((float)s0[j], t1c[0][hp], sa[0][0][j]);
        sa[0][1][j] = fmaf((float)s1[j], t1c[0][hp], sa[0][1][j]);
        sa[1][0][j] = fmaf((float)s0[j], t1c[1][hp], sa[1][0][j]);
        sa[1][1][j] = fmaf((float)s1[j], t1c[1][hp], sa[1][1][j]);
      }
    }
#pragma unroll
    for (int u = 0; u < 2; u++)
#pragma unroll
      for (int mc = 0; mc < 2; mc++) {
        half8 ph;
#pragma unroll
        for (int j = 0; j < 8; j++) ph[j] = (_Float16)EXP2F(sa[u][mc][j]);
        *(half8*)&Pb[LADDR((wv*2+u)*16 + l15, mc*4 + qd)] = ph;
      }
    __syncthreads();

    // (c) th2-mix -> W A-frags in regs -> PV MFMA (V direct from global)
    {
      float wa[2][2][8];
#pragma unroll
      for (int u = 0; u < 2; u++)
#pragma unroll
        for (int mc = 0; mc < 2; mc++)
#pragma unroll
          for (int j = 0; j < 8; j++) wa[u][mc][j] = 0.f;
#pragma unroll
      for (int hp = 0; hp < 8; hp++) {
        half8 p0 = *(const half8*)&Pb[LADDR(hp*16 + l15, qd)];
        half8 p1 = *(const half8*)&Pb[LADDR(hp*16 + l15, 4 + qd)];
#pragma unroll
        for (int j = 0; j < 8; j++) {
          wa[0][0][j] = fmaf((float)p0[j], t2c[0][hp], wa[0][0][j]);
          wa[0][1][j] = fmaf((float)p1[j], t2c[0][hp], wa[0][1][j]);
          wa[1][0][j] = fmaf((float)p0[j], t2c[1][hp], wa[1][0][j]);
          wa[1][1][j] = fmaf((float)p1[j], t2c[1][hp], wa[1][1][j]);
        }
      }
#pragma unroll
      for (int u = 0; u < 2; u++) {
        const int g = wv*2 + u;
#pragma unroll
        for (int mc = 0; mc < 2; mc++) {
          half8 wf;
#pragma unroll
          for (int j = 0; j < 8; j++) wf[j] = (_Float16)wa[u][mc][j];
#pragma unroll
          for (int dt = 0; dt < 4; dt++) {
            half8 vb = *(const half8*)(vbase +
                (size_t)(g*64 + dt*16 + l15)*2048 + mm + mc*32 + qd*8);
            og[u][dt] = MFMA32(wf, vb, og[u][dt]);
          }
        }
      }
    }
    // (a) for iter it+1 (overlaps (c); Sb was fully read before last barrier)
    if (it < 7) {
      const int mmw = mq*512 + (it+1)*64 + wv*16;
#pragma unroll
      for (int h = 0; h < 8; h++) {
        half8 qa0 = *(const half8*)&Qs[LADDR(h*16 + l15, qd)];
        half8 qa1 = *(const half8*)&Qs[LADDR(h*16 + l15, 4 + qd)];
        const _Float16* kp = Kh + ((size_t)((b*8+h)*2048 + mmw + l15))*64 + qd*8;
        half8 kb0 = *(const half8*)kp;
        half8 kb1 = *(const half8*)(kp + 32);
        f32x4 s4 = {0.f,0.f,0.f,0.f};
        s4 = MFMA32(kb0, qa0, s4);
        s4 = MFMA32(kb1, qa1, s4);
        half4 sh;
#pragma unroll
        for (int i = 0; i < 4; i++) sh[i] = (_Float16)s4[i];
        const int row = h*16 + l15;
        const int col = wv*16 + qd*4;
        *(half4*)&Sb[LADDR(row, col >> 3) + (col & 7)] = sh;
      }
    }
    __syncthreads();
  }

  // epilogue: og[u][dt][i] -> (n = n0+qd*4+i, col = (wv*2+u)*64 + dt*16 + l15)
  _Float16* Op = Obuf + (size_t)mq * OPART + ((size_t)(b*2048 + n0))*512;
#pragma unroll
  for (int u = 0; u < 2; u++)
#pragma unroll
    for (int dt = 0; dt < 4; dt++)
#pragma unroll
      for (int i = 0; i < 4; i++)
        Op[(size_t)(qd*4 + i)*512 + (wv*2+u)*64 + dt*16 + l15] = (_Float16)og[u][dt][i];
}

// ---------------------------------------------------------------------------
// K4: output projection summing 4 partial O buffers.
// out[8192,512] = (O0+O1+O2+O3) @ w_out[512,512] + b_out (fp32 out)
// ---------------------------------------------------------------------------
__global__ __launch_bounds__(256)
void k_oproj(const _Float16* __restrict__ Ob, const float* __restrict__ w,
             const float* __restrict__ bias, float* __restrict__ out)
{
  __shared__ __align__(16) _Float16 Xs[64*40];
  __shared__ __align__(16) _Float16 Wt[64*40];
  const int tid = threadIdx.x;
  const int wv = tid >> 6, lane = tid & 63, l15 = lane & 15, qd = lane >> 4;
  const int row0 = blockIdx.x * 64, col0 = blockIdx.y * 64;
  const int xr = tid >> 2, xc = (tid & 3) * 8;
  const int wk = tid >> 3, wc = (tid & 7) * 8;

  f32x4 acc[4] = {{0.f,0.f,0.f,0.f},{0.f,0.f,0.f,0.f},{0.f,0.f,0.f,0.f},{0.f,0.f,0.f,0.f}};

  for (int k0 = 0; k0 < 512; k0 += 32) {
    const size_t idx = (size_t)(row0 + xr)*512 + k0 + xc;
    half8 a0 = *(const half8*)(Ob + idx);
    half8 a1 = *(const half8*)(Ob + OPART + idx);
    half8 a2 = *(const half8*)(Ob + 2*OPART + idx);
    half8 a3 = *(const half8*)(Ob + 3*OPART + idx);
    *(half8*)&Xs[xr*40 + xc] = (a0 + a1) + (a2 + a3);
    f32x4 b0 = *(const f32x4*)(w + (size_t)(k0 + wk)*512 + col0 + wc);
    f32x4 b1 = *(const f32x4*)(w + (size_t)(k0 + wk)*512 + col0 + wc + 4);
#pragma unroll
    for (int j = 0; j < 4; j++) {
      Wt[(wc+j  )*40 + wk] = (_Float16)b0[j];
      Wt[(wc+j+4)*40 + wk] = (_Float16)b1[j];
    }
    __syncthreads();
    half8 af = *(const half8*)&Xs[(wv*16 + l15)*40 + qd*8];
#pragma unroll
    for (int ct = 0; ct < 4; ct++) {
      half8 bf = *(const half8*)&Wt[(ct*16 + l15)*40 + qd*8];
      acc[ct] = MFMA32(af, bf, acc[ct]);
    }
    __syncthreads();
  }
#pragma unroll
  for (int ct = 0; ct < 4; ct++) {
    const int c = col0 + ct*16 + l15;
    const float bv = bias[c];
#pragma unroll
    for (int i = 0; i < 4; i++) {
      const int row = row0 + wv*16 + qd*4 + i;
      out[(size_t)row*512 + c] = acc[ct][i] + bv;
    }
  }
}

// ---------------------------------------------------------------------------
extern "C" void kernel_launch(void* const* d_in, const int* in_sizes, int n_in,
                              void* d_out, int out_size, void* d_ws, size_t ws_size,
                              hipStream_t stream)
{
  (void)in_sizes; (void)n_in; (void)out_size;
  const float* x     = (const float*)d_in[0];
  const float* w_qkv = (const float*)d_in[1];
  const float* b_qkv = (const float*)d_in[2];
  const float* th1   = (const float*)d_in[3];
  const float* th2   = (const float*)d_in[4];
  const float* w_out = (const float*)d_in[5];
  const float* b_out = (const float*)d_in[6];
  float* out = (float*)d_out;

  char* ws = (char*)d_ws;
  _Float16* Qh   = (_Float16*)(ws + QH_OFF);
  _Float16* Kh   = (_Float16*)(ws + KH_OFF);
  _Float16* Vt   = (_Float16*)(ws + VT_OFF);
  float*    Lsum = (float*)   (ws + LS_OFF);
  _Float16* Obuf = (_Float16*)(ws + O_OFF);
  if (ws_size < ((size_t)58 << 20)) return;  // need 58 MB scratch

  k_qkv  <<<dim3(128, 24), 256, 0, stream>>>(x, w_qkv, b_qkv, Qh, Kh, Vt);
  k_pass1<<<dim3(2048),    256, 0, stream>>>(Qh, Kh, th1, Lsum);
  k_pass2<<<dim3(2048),    256, 0, stream>>>(Qh, Kh, Vt, Lsum, th1, th2, Obuf);
  k_oproj<<<dim3(128, 8),  256, 0, stream>>>(Obuf, w_out, b_out, out);
}